// Round 4
// baseline (930.356 us; speedup 1.0000x reference)
//
#include <hip/hip_runtime.h>

#define UU 3000
#define SS 1500
#define TT 32
#define BB 16384
#define KK 50
#define RPT 12   // ceil(3000/256) register keys per thread

// order-preserving float<->uint map
__device__ __forceinline__ unsigned int float_to_key(float f) {
    unsigned int b = __float_as_uint(f);
    return (b & 0x80000000u) ? ~b : (b | 0x80000000u);
}
__device__ __forceinline__ float key_to_float(unsigned int k) {
    return (k & 0x80000000u) ? __uint_as_float(k & 0x7FFFFFFFu)
                             : __uint_as_float(~k);
}

// ---------------------------------------------------------------------------
// Kernel 1: per-user top-50 via 4-pass 8-bit radix select, keys in REGISTERS.
// Block u < UU: top-50 of user_sim row u -> interleaved (idx, val_bits) pairs.
// Block u == UU: classify mask buffer encoding into *flag.
// hist is split 4 ways by wave to cut same-bin LDS-atomic serialization
// (uniform values concentrate in a few exponent bins).
// ---------------------------------------------------------------------------
__global__ __launch_bounds__(256) void topk_select(const float* __restrict__ user_sim,
                                                   int2* __restrict__ topk,
                                                   const unsigned int* __restrict__ mask,
                                                   int* __restrict__ flag) {
    const int u = blockIdx.x;

    if (u == UU) {   // ---- mask-encoding probe ----
        __shared__ int bad_i32, bad_f32;
        if (threadIdx.x == 0) { bad_i32 = 0; bad_f32 = 0; }
        __syncthreads();
        for (int i = threadIdx.x; i < 4096; i += 256) {
            unsigned int w = mask[i];
            if (w > 1u) bad_i32 = 1;
            if (w != 0u && w != 0x3F800000u) bad_f32 = 1;
        }
        __syncthreads();
        if (threadIdx.x == 0) {
            int f = 0;
            if (bad_i32) f = bad_f32 ? 1 : 2;
            *flag = f;
        }
        return;
    }

    __shared__ int hist[4][256];
    __shared__ int s_bin, s_rem;
    __shared__ int cnt_gt, eq_cnt;
    __shared__ int eq_list[64];

    const float* row = user_sim + (size_t)u * UU;
    const int wv_id = threadIdx.x >> 6;

    unsigned int keys[RPT];
    #pragma unroll
    for (int j = 0; j < RPT; ++j) {
        const int i = threadIdx.x + 256 * j;
        keys[j] = (i < UU) ? float_to_key(row[i]) : 0u;
    }
    if (threadIdx.x == 0) { cnt_gt = 0; eq_cnt = 0; }

    unsigned int prefix = 0u, prefmask = 0u;
    int remaining = KK;

    for (int pass = 0; pass < 4; ++pass) {
        const int shift = 24 - pass * 8;
        #pragma unroll
        for (int w = 0; w < 4; ++w) hist[w][threadIdx.x] = 0;
        __syncthreads();
        #pragma unroll
        for (int j = 0; j < RPT; ++j) {
            const unsigned int k = keys[j];
            if ((k & prefmask) == prefix)
                atomicAdd(&hist[wv_id][(k >> shift) & 0xFFu], 1);
        }
        __syncthreads();
        // wave 0: suffix-scan 256 bins (4 bins/lane), find threshold bin
        if (threadIdx.x < 64) {
            const int lane = threadIdx.x;
            int hb[4];
            #pragma unroll
            for (int b = 0; b < 4; ++b)
                hb[b] = hist[0][4*lane+b] + hist[1][4*lane+b]
                      + hist[2][4*lane+b] + hist[3][4*lane+b];
            const int local = hb[0] + hb[1] + hb[2] + hb[3];
            int x = local;                       // inclusive suffix sum over lanes
            for (int off = 1; off < 64; off <<= 1) {
                int y = __shfl_down(x, off, 64);
                if (lane + off < 64) x += y;
            }
            const int excl = x - local;          // keys in strictly higher lane-groups
            if (excl < remaining && remaining <= excl + local) {
                int acc = excl;
                #pragma unroll
                for (int jj = 3; jj >= 0; --jj) {   // descending bins
                    if (acc + hb[jj] >= remaining) {
                        s_bin = 4 * lane + jj;
                        s_rem = remaining - acc;
                        break;
                    }
                    acc += hb[jj];
                }
            }
        }
        __syncthreads();
        prefix  |= ((unsigned int)s_bin) << shift;
        prefmask |= (0xFFu << shift);
        remaining = s_rem;
        // no trailing barrier: next write to s_bin/s_rem is >=1 barrier away
    }

    const unsigned int thr = prefix;   // exact key of the boundary element
    #pragma unroll
    for (int j = 0; j < RPT; ++j) {
        const unsigned int k = keys[j];
        const int i = threadIdx.x + 256 * j;
        if (k > thr) {
            int p = atomicAdd(&cnt_gt, 1);
            topk[u * KK + p] = make_int2(i, __float_as_int(key_to_float(k)));
        } else if (k == thr) {
            int e = atomicAdd(&eq_cnt, 1);
            if (e < 64) eq_list[e] = i;
        }
    }
    __syncthreads();
    if (threadIdx.x == 0) {
        // fill slots [KK-remaining, KK) with smallest-index ties (jax tie-break)
        const int n = eq_cnt < 64 ? eq_cnt : 64;
        const int vb = __float_as_int(key_to_float(thr));
        const int base = KK - remaining;
        for (int r = 0; r < remaining; ++r) {
            int mi = -1, mv = 0x7FFFFFFF;
            for (int jj = 0; jj < n; ++jj) {
                int v = eq_list[jj];
                if (v >= 0 && v < mv) { mv = v; mi = jj; }
            }
            eq_list[mi] = -1;
            topk[u * KK + base + r] = make_int2(mv, vb);
        }
    }
}

// ---------------------------------------------------------------------------
// Kernel 2: one 64-lane wave per TWO batch elements (e0 = wave, e1 = wave +
// BB/2). Lanes 0..49 gather one neighbor of each element -> 6 independent
// scattered loads in flight per lane; butterfly-reduce both sums at once.
// ---------------------------------------------------------------------------
__global__ __launch_bounds__(256) void gather_kernel(
    const float* __restrict__ qos, const void* __restrict__ mask,
    const float* __restrict__ avg, const int* __restrict__ time_ids,
    const int* __restrict__ user_ids, const int* __restrict__ service_ids,
    const int2* __restrict__ topk, const int* __restrict__ flag,
    float* __restrict__ out) {

    const int wave = (int)((blockIdx.x * blockDim.x + threadIdx.x) >> 6);
    const int lane = (int)(threadIdx.x & 63);
    const int e0 = wave;
    const int e1 = wave + BB / 2;

    const int u0 = user_ids[e0],    u1 = user_ids[e1];
    const int s0 = service_ids[e0], s1 = service_ids[e1];
    const int t0 = time_ids[e0],    t1 = time_ids[e1];
    const float base0 = avg[(size_t)u0 * SS + s0];
    const float base1 = avg[(size_t)u1 * SS + s1];
    const int fl = *flag;   // wave-uniform, L2-hot

    float wv0 = 0.0f, dv0 = 0.0f, wv1 = 0.0f, dv1 = 0.0f;
    if (lane < KK) {
        const int2 tv0 = topk[u0 * KK + lane];
        const int2 tv1 = topk[u1 * KK + lane];
        const size_t off0 = ((size_t)tv0.x * SS + s0) * TT + t0;
        const size_t off1 = ((size_t)tv1.x * SS + s1) * TT + t1;
        const float q0 = qos[off0];
        const float q1 = qos[off1];
        const float a0 = avg[(size_t)tv0.x * SS + s0];
        const float a1 = avg[(size_t)tv1.x * SS + s1];
        int m0, m1;
        if (fl == 0) {
            m0 = ((const int*)mask)[off0];
            m1 = ((const int*)mask)[off1];
        } else if (fl == 1) {
            m0 = (int)((const unsigned char*)mask)[off0];
            m1 = (int)((const unsigned char*)mask)[off1];
        } else {
            m0 = (((const float*)mask)[off0] != 0.0f) ? 1 : 0;
            m1 = (((const float*)mask)[off1] != 0.0f) ? 1 : 0;
        }
        const float val0 = __int_as_float(tv0.y);
        const float val1 = __int_as_float(tv1.y);
        wv0 = m0 ? val0 : 0.0f;
        dv0 = m0 ? val0 * (q0 - a0) : 0.0f;
        wv1 = m1 ? val1 : 0.0f;
        dv1 = m1 ? val1 * (q1 - a1) : 0.0f;
    }
    for (int m2 = 32; m2 >= 1; m2 >>= 1) {
        wv0 += __shfl_xor(wv0, m2, 64);
        dv0 += __shfl_xor(dv0, m2, 64);
        wv1 += __shfl_xor(wv1, m2, 64);
        dv1 += __shfl_xor(dv1, m2, 64);
    }
    if (lane == 0) {
        const float dev0 = (wv0 > 0.0f) ? (dv0 / wv0) : 0.0f;
        const float dev1 = (wv1 > 0.0f) ? (dv1 / wv1) : 0.0f;
        const float r0 = base0 + dev0;
        const float r1 = base1 + dev1;
        out[e0] = (r0 > 0.0f) ? r0 : 0.0f;
        out[e1] = (r1 > 0.0f) ? r1 : 0.0f;
    }
}

extern "C" void kernel_launch(void* const* d_in, const int* in_sizes, int n_in,
                              void* d_out, int out_size, void* d_ws, size_t ws_size,
                              hipStream_t stream) {
    const float* qos      = (const float*)d_in[0];
    const void*  mask     = d_in[1];
    const float* avg      = (const float*)d_in[2];
    const float* user_sim = (const float*)d_in[3];
    const int* time_ids    = (const int*)d_in[4];
    const int* user_ids    = (const int*)d_in[5];
    const int* service_ids = (const int*)d_in[6];
    float* out = (float*)d_out;

    // ws layout: [topk pairs: U*K int2][flag: int]
    int2* topk = (int2*)d_ws;
    int*  flag = (int*)((char*)d_ws + (size_t)UU * KK * 8);

    topk_select<<<UU + 1, 256, 0, stream>>>(user_sim, topk,
                                            (const unsigned int*)mask, flag);
    gather_kernel<<<(BB / 2 * 64) / 256, 256, 0, stream>>>(
        qos, mask, avg, time_ids, user_ids, service_ids, topk, flag, out);
}